// Round 2
// baseline (276.856 us; speedup 1.0000x reference)
//
#include <hip/hip_runtime.h>
#include <hip/hip_bf16.h>

// Problem constants (EmbDotSoftMax): B=4096, N_CITY=50, EC=128, VOCAB=40000
#define NC       50
#define EC       128
#define VOCAB    40000
#define BM_WORDS ((VOCAB + 31) / 32)   // 1250 u32 = 5 KB bitmap

// One block per batch row, 128 threads (2 waves).
// Key idea: NO atomics, NO fill->scatter drain barrier. A 5KB LDS bitmap marks
// the 50 scatter targets; the 1e-6 fill SKIPS marked elements, and owner
// threads (first occurrence per id, duplicates pre-combined in LDS) write
// p_sum + 1e-6 with plain stores. Zero address overlap -> no ordering needed;
// blocks retire with stores still in flight.
__global__ __launch_bounds__(128)
void EmbDotSoftMax_fused_kernel(const float* __restrict__ x,
                                const float* __restrict__ emb,
                                const int*   __restrict__ ids,
                                const float* __restrict__ W,
                                const float* __restrict__ bias,
                                float*       __restrict__ out)
{
    const int b   = blockIdx.x;
    const int tid = threadIdx.x;

    __shared__ unsigned int bm[BM_WORDS];
    __shared__ float4 x_s4[EC / 4];
    __shared__ float  pred_s[EC];
    __shared__ float  scores_s[NC];
    __shared__ float  p_s[NC];
    __shared__ int    id_s[NC];

    float* out_row = out + (size_t)b * VOCAB;

    // ---- Phase 0: zero bitmap, stage x and ids ----
    #pragma unroll
    for (int i = tid; i < BM_WORDS; i += 128) bm[i] = 0u;
    if (tid < EC / 4)
        x_s4[tid] = reinterpret_cast<const float4*>(x + (size_t)b * EC)[tid];
    if (tid < NC)
        id_s[tid] = ids[(size_t)b * NC + tid];
    __syncthreads();

    // ---- Phase 1: emb_pred = x @ W^T + bias (thread tid owns element tid) ----
    {
        float acc = 0.0f;
        const float4* Wrow = reinterpret_cast<const float4*>(W + (size_t)tid * EC);
        #pragma unroll
        for (int k = 0; k < EC / 4; ++k) {
            float4 w4 = Wrow[k];
            float4 xv = x_s4[k];
            acc = fmaf(w4.x, xv.x, acc);
            acc = fmaf(w4.y, xv.y, acc);
            acc = fmaf(w4.z, xv.z, acc);
            acc = fmaf(w4.w, xv.w, acc);
        }
        pred_s[tid] = acc + bias[tid];
    }
    __syncthreads();

    // ---- Phase 2: scores. Wave w handles cities [w*25, w*25+25).
    // All 50 loads issued up front (MLP), then 25 independent butterfly
    // reduce chains (pipelined), lane 0 writes with compile-time indices. ----
    {
        const int w = tid >> 6;
        const int l = tid & 63;
        const float p0 = pred_s[l];
        const float p1 = pred_s[l + 64];
        const float* base = emb + (size_t)b * NC * EC + (size_t)w * (NC / 2) * EC;

        float part[NC / 2];
        #pragma unroll
        for (int i = 0; i < NC / 2; ++i) {
            const float* er = base + i * EC;
            part[i] = fmaf(p0, er[l], p1 * er[l + 64]);
        }
        #pragma unroll
        for (int off = 32; off; off >>= 1) {
            #pragma unroll
            for (int i = 0; i < NC / 2; ++i)
                part[i] += __shfl_xor(part[i], off);
        }
        if (l == 0) {
            #pragma unroll
            for (int i = 0; i < NC / 2; ++i)
                scores_s[w * (NC / 2) + i] = part[i];
        }
    }
    __syncthreads();

    // ---- Phase 3: softmax over 50 + mark bitmap (LDS atomics only) ----
    if (tid < NC) {
        float m = -1e30f;
        #pragma unroll
        for (int n = 0; n < NC; ++n) m = fmaxf(m, scores_s[n]);
        float sum = 0.0f;
        #pragma unroll
        for (int n = 0; n < NC; ++n) sum += __expf(scores_s[n] - m);
        p_s[tid] = __expf(scores_s[tid] - m) / sum;
        const int id = id_s[tid];
        atomicOr(&bm[id >> 5], 1u << (id & 31));
    }
    __syncthreads();   // only LDS + consumed loads outstanding -> cheap barrier

    // ---- Phase 4: fill row with 1e-6, skipping marked elements ----
    {
        const float4 fv = make_float4(1e-6f, 1e-6f, 1e-6f, 1e-6f);
        float4* out4 = reinterpret_cast<float4*>(out_row);  // rows are 16B-aligned (VOCAB%4==0)
        for (int i = tid; i < VOCAB / 4; i += 128) {
            // element base 4i: word (4i)>>5 = i>>3, shift (4i)&31 = (i&7)*4
            const unsigned bits = (bm[i >> 3] >> ((i & 7) << 2)) & 0xFu;
            if (bits == 0u) {
                out4[i] = fv;
            } else {
                #pragma unroll
                for (int e = 0; e < 4; ++e)
                    if (!(bits & (1u << e))) out_row[4 * i + e] = 1e-6f;
            }
        }
    }

    // ---- Phase 5: owner threads write combined prob (plain stores, disjoint
    //               from fill addresses) ----
    if (tid < NC) {
        const int myid = id_s[tid];
        int   first = tid;
        float sum   = 0.0f;
        #pragma unroll
        for (int j = 0; j < NC; ++j) {
            if (id_s[j] == myid) {
                if (j < first) first = j;
                sum += p_s[j];
            }
        }
        if (first == tid)
            out_row[myid] = sum + 1e-6f;
    }
    // no trailing barrier: block retires with stores in flight
}

extern "C" void kernel_launch(void* const* d_in, const int* in_sizes, int n_in,
                              void* d_out, int out_size, void* d_ws, size_t ws_size,
                              hipStream_t stream) {
    const float* x    = (const float*)d_in[0];
    const float* emb  = (const float*)d_in[1];
    const int*   ids  = (const int*)d_in[2];
    // d_in[3] = prob (zeros) — unused, output built from scratch
    const float* W    = (const float*)d_in[4];
    const float* bias = (const float*)d_in[5];
    float*       out  = (float*)d_out;

    const int B = in_sizes[0] / EC;    // 4096

    hipLaunchKernelGGL(EmbDotSoftMax_fused_kernel,
                       dim3(B), dim3(128), 0, stream,
                       x, emb, ids, W, bias, out);
}

// Round 3
// 227.802 us; speedup vs baseline: 1.2153x; 1.2153x over previous
//
#include <hip/hip_runtime.h>
#include <hip/hip_bf16.h>

// Problem constants (EmbDotSoftMax): B=4096, N_CITY=50, EC=128, VOCAB=40000
#define NC    50
#define EC    128
#define VOCAB 40000

// ---------------- Kernel 1: pure 1e-6 fill (fillBuffer-shaped) ----------------
// The 655 MB store stream is the critical path; keep it maximally dumb.
// Grid-stride float4 stores, nothing else. Measured machine ceiling for this
// exact shape: 6.6-6.9 TB/s (harness fillBufferAligned).
__global__ __launch_bounds__(256)
void EmbDotSoftMax_fill_kernel(float4* __restrict__ out4, long n4)
{
    const float4 fv = make_float4(1e-6f, 1e-6f, 1e-6f, 1e-6f);
    long idx    = (long)blockIdx.x * 256 + threadIdx.x;
    const long stride = (long)gridDim.x * 256;
    for (; idx < n4; idx += stride)
        out4[idx] = fv;
}

// ---------------- Kernel 2: compute + atomic scatter ----------------
// One block per batch row, 128 threads (2 waves). Stream ordering puts this
// after the fill, so atomics just add onto the 1e-6 base. No drain barriers.
__global__ __launch_bounds__(128)
void EmbDotSoftMax_scatter_kernel(const float* __restrict__ x,
                                  const float* __restrict__ emb,
                                  const int*   __restrict__ ids,
                                  const float* __restrict__ W,
                                  const float* __restrict__ bias,
                                  float*       __restrict__ out)
{
    const int b   = blockIdx.x;
    const int tid = threadIdx.x;

    __shared__ float4 x_s4[EC / 4];
    __shared__ float  pred_s[EC];
    __shared__ float  scores_s[NC];

    float* out_row = out + (size_t)b * VOCAB;

    // ---- stage x[b] ----
    if (tid < EC / 4)
        x_s4[tid] = reinterpret_cast<const float4*>(x + (size_t)b * EC)[tid];
    __syncthreads();

    // ---- emb_pred = x @ W^T + bias (thread tid owns element tid; W L2-resident) ----
    {
        float acc = 0.0f;
        const float4* Wrow = reinterpret_cast<const float4*>(W + (size_t)tid * EC);
        #pragma unroll
        for (int k = 0; k < EC / 4; ++k) {
            float4 w4 = Wrow[k];
            float4 xv = x_s4[k];
            acc = fmaf(w4.x, xv.x, acc);
            acc = fmaf(w4.y, xv.y, acc);
            acc = fmaf(w4.z, xv.z, acc);
            acc = fmaf(w4.w, xv.w, acc);
        }
        pred_s[tid] = acc + bias[tid];
    }
    __syncthreads();

    // ---- scores: wave w owns cities [w*25, w*25+25). All 50 loads issued
    //      up front, then 25 independent butterfly reduce chains. ----
    {
        const int w = tid >> 6;
        const int l = tid & 63;
        const float p0 = pred_s[l];
        const float p1 = pred_s[l + 64];
        const float* base = emb + (size_t)b * NC * EC + (size_t)w * (NC / 2) * EC;

        float part[NC / 2];
        #pragma unroll
        for (int i = 0; i < NC / 2; ++i) {
            const float* er = base + i * EC;
            part[i] = fmaf(p0, er[l], p1 * er[l + 64]);
        }
        #pragma unroll
        for (int off = 32; off; off >>= 1) {
            #pragma unroll
            for (int i = 0; i < NC / 2; ++i)
                part[i] += __shfl_xor(part[i], off);
        }
        if (l == 0) {
            #pragma unroll
            for (int i = 0; i < NC / 2; ++i)
                scores_s[w * (NC / 2) + i] = part[i];
        }
    }
    __syncthreads();

    // ---- softmax over 50 + atomic scatter (duplicates handled by atomics) ----
    if (tid < NC) {
        float m = -1e30f;
        #pragma unroll
        for (int n = 0; n < NC; ++n) m = fmaxf(m, scores_s[n]);
        float sum = 0.0f;
        #pragma unroll
        for (int n = 0; n < NC; ++n) sum += __expf(scores_s[n] - m);
        const float p  = __expf(scores_s[tid] - m) / sum;
        const int   id = ids[(size_t)b * NC + tid];
        atomicAdd(out_row + id, p);
    }
}

extern "C" void kernel_launch(void* const* d_in, const int* in_sizes, int n_in,
                              void* d_out, int out_size, void* d_ws, size_t ws_size,
                              hipStream_t stream) {
    const float* x    = (const float*)d_in[0];
    const float* emb  = (const float*)d_in[1];
    const int*   ids  = (const int*)d_in[2];
    // d_in[3] = prob (zeros) — unused
    const float* W    = (const float*)d_in[4];
    const float* bias = (const float*)d_in[5];
    float*       out  = (float*)d_out;

    const int B = in_sizes[0] / EC;    // 4096

    const long n4 = (long)B * VOCAB / 4;   // 40,960,000 float4
    hipLaunchKernelGGL(EmbDotSoftMax_fill_kernel,
                       dim3(2048), dim3(256), 0, stream,
                       reinterpret_cast<float4*>(out), n4);

    hipLaunchKernelGGL(EmbDotSoftMax_scatter_kernel,
                       dim3(B), dim3(128), 0, stream,
                       x, emb, ids, W, bias, out);
}

// Round 4
// 213.171 us; speedup vs baseline: 1.2988x; 1.0686x over previous
//
#include <hip/hip_runtime.h>
#include <hip/hip_bf16.h>

// Problem constants (EmbDotSoftMax): B=4096, N_CITY=50, EC=128, VOCAB=40000
#define NC    50
#define EC    128
#define VOCAB 40000

// ---------------- Kernel A: compute softmax probs -> ws ----------------
// One block per batch row, 128 threads. Identical to R3's scatter kernel
// except the result goes to ws (no interaction with the big store stream).
__global__ __launch_bounds__(128)
void EmbDotSoftMax_compute_kernel(const float* __restrict__ x,
                                  const float* __restrict__ emb,
                                  const float* __restrict__ W,
                                  const float* __restrict__ bias,
                                  float*       __restrict__ pws)
{
    const int b   = blockIdx.x;
    const int tid = threadIdx.x;

    __shared__ float4 x_s4[EC / 4];
    __shared__ float  pred_s[EC];
    __shared__ float  scores_s[NC];

    if (tid < EC / 4)
        x_s4[tid] = reinterpret_cast<const float4*>(x + (size_t)b * EC)[tid];
    __syncthreads();

    {
        float acc = 0.0f;
        const float4* Wrow = reinterpret_cast<const float4*>(W + (size_t)tid * EC);
        #pragma unroll
        for (int k = 0; k < EC / 4; ++k) {
            float4 w4 = Wrow[k];
            float4 xv = x_s4[k];
            acc = fmaf(w4.x, xv.x, acc);
            acc = fmaf(w4.y, xv.y, acc);
            acc = fmaf(w4.z, xv.z, acc);
            acc = fmaf(w4.w, xv.w, acc);
        }
        pred_s[tid] = acc + bias[tid];
    }
    __syncthreads();

    {
        const int w = tid >> 6;
        const int l = tid & 63;
        const float p0 = pred_s[l];
        const float p1 = pred_s[l + 64];
        const float* base = emb + (size_t)b * NC * EC + (size_t)w * (NC / 2) * EC;

        float part[NC / 2];
        #pragma unroll
        for (int i = 0; i < NC / 2; ++i) {
            const float* er = base + i * EC;
            part[i] = fmaf(p0, er[l], p1 * er[l + 64]);
        }
        #pragma unroll
        for (int off = 32; off; off >>= 1) {
            #pragma unroll
            for (int i = 0; i < NC / 2; ++i)
                part[i] += __shfl_xor(part[i], off);
        }
        if (l == 0) {
            #pragma unroll
            for (int i = 0; i < NC / 2; ++i)
                scores_s[w * (NC / 2) + i] = part[i];
        }
    }
    __syncthreads();

    if (tid < NC) {
        float m = -1e30f;
        #pragma unroll
        for (int n = 0; n < NC; ++n) m = fmaxf(m, scores_s[n]);
        float sum = 0.0f;
        #pragma unroll
        for (int n = 0; n < NC; ++n) sum += __expf(scores_s[n] - m);
        pws[(size_t)b * NC + tid] = __expf(scores_s[tid] - m) / sum;
    }
}

// ---------------- Kernel B: exact-cover 1e-6 fill ----------------
// 2500 blocks x 256 threads x 16 iters x 4 independent float4 stores
// = 40,960,000 float4 exactly (no bounds checks, no tail).
__global__ __launch_bounds__(256)
void EmbDotSoftMax_fill_kernel(float4* __restrict__ out4)
{
    const float4 fv = make_float4(1e-6f, 1e-6f, 1e-6f, 1e-6f);
    const long stride = 2500L * 1024;          // grid covers 2.56M f4 per sweep
    long base = (long)blockIdx.x * 1024 + threadIdx.x;
    #pragma unroll 4
    for (int it = 0; it < 16; ++it, base += stride) {
        out4[base          ] = fv;
        out4[base + 256    ] = fv;
        out4[base + 512    ] = fv;
        out4[base + 768    ] = fv;
    }
}

// ---------------- Kernel C: merge probs into out (atomics) ----------------
// One thread per (b, n); coalesced reads of ids/p; 204,800 atomicAdds.
__global__ __launch_bounds__(256)
void EmbDotSoftMax_merge_kernel(const int*   __restrict__ ids,
                                const float* __restrict__ pws,
                                float*       __restrict__ out)
{
    const int t = blockIdx.x * 256 + threadIdx.x;
    if (t < 4096 * NC) {
        const int   b  = t / NC;
        const int   id = ids[t];
        const float p  = pws[t];
        atomicAdd(out + (size_t)b * VOCAB + id, p);
    }
}

// ---------------- Fallback (ws too small): R3's fused scatter ----------------
__global__ __launch_bounds__(128)
void EmbDotSoftMax_scatter_fb(const float* __restrict__ x,
                              const float* __restrict__ emb,
                              const int*   __restrict__ ids,
                              const float* __restrict__ W,
                              const float* __restrict__ bias,
                              float*       __restrict__ out)
{
    const int b   = blockIdx.x;
    const int tid = threadIdx.x;
    __shared__ float4 x_s4[EC / 4];
    __shared__ float  pred_s[EC];
    __shared__ float  scores_s[NC];
    float* out_row = out + (size_t)b * VOCAB;
    if (tid < EC / 4)
        x_s4[tid] = reinterpret_cast<const float4*>(x + (size_t)b * EC)[tid];
    __syncthreads();
    {
        float acc = 0.0f;
        const float4* Wrow = reinterpret_cast<const float4*>(W + (size_t)tid * EC);
        #pragma unroll
        for (int k = 0; k < EC / 4; ++k) {
            float4 w4 = Wrow[k];
            float4 xv = x_s4[k];
            acc = fmaf(w4.x, xv.x, acc); acc = fmaf(w4.y, xv.y, acc);
            acc = fmaf(w4.z, xv.z, acc); acc = fmaf(w4.w, xv.w, acc);
        }
        pred_s[tid] = acc + bias[tid];
    }
    __syncthreads();
    {
        const int w = tid >> 6;
        const int l = tid & 63;
        const float p0 = pred_s[l];
        const float p1 = pred_s[l + 64];
        const float* base = emb + (size_t)b * NC * EC + (size_t)w * (NC / 2) * EC;
        float part[NC / 2];
        #pragma unroll
        for (int i = 0; i < NC / 2; ++i) {
            const float* er = base + i * EC;
            part[i] = fmaf(p0, er[l], p1 * er[l + 64]);
        }
        #pragma unroll
        for (int off = 32; off; off >>= 1) {
            #pragma unroll
            for (int i = 0; i < NC / 2; ++i)
                part[i] += __shfl_xor(part[i], off);
        }
        if (l == 0) {
            #pragma unroll
            for (int i = 0; i < NC / 2; ++i)
                scores_s[w * (NC / 2) + i] = part[i];
        }
    }
    __syncthreads();
    if (tid < NC) {
        float m = -1e30f;
        #pragma unroll
        for (int n = 0; n < NC; ++n) m = fmaxf(m, scores_s[n]);
        float sum = 0.0f;
        #pragma unroll
        for (int n = 0; n < NC; ++n) sum += __expf(scores_s[n] - m);
        const float p  = __expf(scores_s[tid] - m) / sum;
        atomicAdd(out_row + ids[(size_t)b * NC + tid], p);
    }
}

extern "C" void kernel_launch(void* const* d_in, const int* in_sizes, int n_in,
                              void* d_out, int out_size, void* d_ws, size_t ws_size,
                              hipStream_t stream) {
    const float* x    = (const float*)d_in[0];
    const float* emb  = (const float*)d_in[1];
    const int*   ids  = (const int*)d_in[2];
    // d_in[3] = prob (zeros) — unused
    const float* W    = (const float*)d_in[4];
    const float* bias = (const float*)d_in[5];
    float*       out  = (float*)d_out;

    const int B = in_sizes[0] / EC;    // 4096
    const size_t ws_needed = (size_t)B * NC * sizeof(float);   // 800 KB

    if (ws_size >= ws_needed) {
        float* pws = (float*)d_ws;
        hipLaunchKernelGGL(EmbDotSoftMax_compute_kernel,
                           dim3(B), dim3(128), 0, stream,
                           x, emb, W, bias, pws);
        hipLaunchKernelGGL(EmbDotSoftMax_fill_kernel,
                           dim3(2500), dim3(256), 0, stream,
                           reinterpret_cast<float4*>(out));
        hipLaunchKernelGGL(EmbDotSoftMax_merge_kernel,
                           dim3((B * NC + 255) / 256), dim3(256), 0, stream,
                           ids, pws, out);
    } else {
        hipLaunchKernelGGL(EmbDotSoftMax_fill_kernel,
                           dim3(2500), dim3(256), 0, stream,
                           reinterpret_cast<float4*>(out));
        hipLaunchKernelGGL(EmbDotSoftMax_scatter_fb,
                           dim3(B), dim3(128), 0, stream,
                           x, emb, ids, W, bias, out);
    }
}

// Round 6
// 186.808 us; speedup vs baseline: 1.4820x; 1.1411x over previous
//
#include <hip/hip_runtime.h>
#include <hip/hip_bf16.h>

// Problem constants (EmbDotSoftMax): B=4096, N_CITY=50, EC=128, VOCAB=40000
#define NC          50
#define EC          128
#define VOCAB       40000
#define FILL_BLOCKS 6400   // x128 threads = 819200 fill threads

typedef float f4_t __attribute__((ext_vector_type(4)));   // native vec for nt-store

// ---------------- Kernel 1: HYBRID fill + compute ----------------
// Fill blocks (blockIdx < FILL_BLOCKS) stream 1e-6 into out (nt stores).
// Compute blocks (blockIdx >= FILL_BLOCKS) compute softmax probs -> ws.
// Disjoint outputs (out vs ws) -> no ordering needed; the compute blocks'
// 100 MB of emb reads overlap the 655 MB store stream instead of
// serializing after it.
//
// Compute GEMV is COALESCED (the R1-R4 mistake was per-thread W-row reads,
// 64 cache lines per load instruction): wave reads W row e contiguously
// (256B x2), butterfly shfl_xor reduce, lane (e&63) keeps the sum.
__global__ __launch_bounds__(128)
void EmbDotSoftMax_hybrid_kernel(const float* __restrict__ x,
                                 const float* __restrict__ emb,
                                 const float* __restrict__ W,
                                 const float* __restrict__ bias,
                                 float*       __restrict__ out,
                                 float*       __restrict__ pws,
                                 long n4)
{
    const int tid = threadIdx.x;

    if (blockIdx.x < FILL_BLOCKS) {
        // ---------------- fill role: dumb nt store stream ----------------
        const f4_t fv = {1e-6f, 1e-6f, 1e-6f, 1e-6f};
        f4_t* out4 = reinterpret_cast<f4_t*>(out);
        const long nthreads = (long)FILL_BLOCKS * 128;
        long idx = (long)blockIdx.x * 128 + tid;
        #pragma unroll 5
        for (; idx < n4; idx += nthreads)
            __builtin_nontemporal_store(fv, out4 + idx);
        return;
    }

    // ---------------- compute role: one row per block ----------------
    const int b = blockIdx.x - FILL_BLOCKS;
    const int w = tid >> 6;          // wave 0/1
    const int l = tid & 63;          // lane

    __shared__ float pred_s[EC];
    __shared__ float scores_s[NC];

    // GEMV: wave w computes pred[e] for e in [w*64, w*64+64).
    // Coalesced W reads; butterfly leaves the full sum in every lane;
    // lane i keeps iteration i's result.
    {
        const float x0 = x[(size_t)b * EC + l];
        const float x1 = x[(size_t)b * EC + 64 + l];
        const float* Wbase = W + (size_t)w * 64 * EC;
        float mine = 0.0f;
        #pragma unroll 8
        for (int i = 0; i < 64; ++i) {
            const float* row = Wbase + i * EC;
            float part = fmaf(x0, row[l], x1 * row[l + 64]);
            #pragma unroll
            for (int off = 32; off; off >>= 1)
                part += __shfl_xor(part, off);
            if (i == l) mine = part;
        }
        pred_s[w * 64 + l] = mine + bias[w * 64 + l];
    }
    __syncthreads();

    // scores: wave w owns cities [w*25, w*25+25); loads issued up front,
    // 25 independent butterfly chains.
    {
        const float p0 = pred_s[l];
        const float p1 = pred_s[l + 64];
        const float* base = emb + (size_t)b * NC * EC + (size_t)w * (NC / 2) * EC;

        float part[NC / 2];
        #pragma unroll
        for (int i = 0; i < NC / 2; ++i) {
            const float* er = base + i * EC;
            part[i] = fmaf(p0, er[l], p1 * er[l + 64]);
        }
        #pragma unroll
        for (int off = 32; off; off >>= 1) {
            #pragma unroll
            for (int i = 0; i < NC / 2; ++i)
                part[i] += __shfl_xor(part[i], off);
        }
        if (l == 0) {
            #pragma unroll
            for (int i = 0; i < NC / 2; ++i)
                scores_s[w * (NC / 2) + i] = part[i];
        }
    }
    __syncthreads();

    // softmax over 50 -> ws
    if (tid < NC) {
        float m = -1e30f;
        #pragma unroll
        for (int n = 0; n < NC; ++n) m = fmaxf(m, scores_s[n]);
        float sum = 0.0f;
        #pragma unroll
        for (int n = 0; n < NC; ++n) sum += __expf(scores_s[n] - m);
        pws[(size_t)b * NC + tid] = __expf(scores_s[tid] - m) / sum;
    }
}

// ---------------- Kernel 2: merge probs into out (atomics) ----------------
__global__ __launch_bounds__(256)
void EmbDotSoftMax_merge_kernel(const int*   __restrict__ ids,
                                const float* __restrict__ pws,
                                float*       __restrict__ out,
                                int total)
{
    const int t = blockIdx.x * 256 + threadIdx.x;
    if (t < total) {
        const int   b  = t / NC;
        const int   id = ids[t];
        const float p  = pws[t];
        atomicAdd(out + (size_t)b * VOCAB + id, p);
    }
}

// ---------------- Fallback (ws too small): fill then fused scatter ----------------
__global__ __launch_bounds__(256)
void EmbDotSoftMax_fill_fb(float4* __restrict__ out4, long n4)
{
    const float4 fv = make_float4(1e-6f, 1e-6f, 1e-6f, 1e-6f);
    long idx = (long)blockIdx.x * 256 + threadIdx.x;
    const long stride = (long)gridDim.x * 256;
    for (; idx < n4; idx += stride)
        out4[idx] = fv;
}

__global__ __launch_bounds__(128)
void EmbDotSoftMax_scatter_fb(const float* __restrict__ x,
                              const float* __restrict__ emb,
                              const int*   __restrict__ ids,
                              const float* __restrict__ W,
                              const float* __restrict__ bias,
                              float*       __restrict__ out)
{
    const int b   = blockIdx.x;
    const int tid = threadIdx.x;
    const int w = tid >> 6;
    const int l = tid & 63;
    __shared__ float pred_s[EC];
    __shared__ float scores_s[NC];
    float* out_row = out + (size_t)b * VOCAB;
    {
        const float x0 = x[(size_t)b * EC + l];
        const float x1 = x[(size_t)b * EC + 64 + l];
        const float* Wbase = W + (size_t)w * 64 * EC;
        float mine = 0.0f;
        #pragma unroll 8
        for (int i = 0; i < 64; ++i) {
            const float* row = Wbase + i * EC;
            float part = fmaf(x0, row[l], x1 * row[l + 64]);
            #pragma unroll
            for (int off = 32; off; off >>= 1)
                part += __shfl_xor(part, off);
            if (i == l) mine = part;
        }
        pred_s[w * 64 + l] = mine + bias[w * 64 + l];
    }
    __syncthreads();
    {
        const float p0 = pred_s[l];
        const float p1 = pred_s[l + 64];
        const float* base = emb + (size_t)b * NC * EC + (size_t)w * (NC / 2) * EC;
        float part[NC / 2];
        #pragma unroll
        for (int i = 0; i < NC / 2; ++i) {
            const float* er = base + i * EC;
            part[i] = fmaf(p0, er[l], p1 * er[l + 64]);
        }
        #pragma unroll
        for (int off = 32; off; off >>= 1) {
            #pragma unroll
            for (int i = 0; i < NC / 2; ++i)
                part[i] += __shfl_xor(part[i], off);
        }
        if (l == 0) {
            #pragma unroll
            for (int i = 0; i < NC / 2; ++i)
                scores_s[w * (NC / 2) + i] = part[i];
        }
    }
    __syncthreads();
    if (tid < NC) {
        float m = -1e30f;
        #pragma unroll
        for (int n = 0; n < NC; ++n) m = fmaxf(m, scores_s[n]);
        float sum = 0.0f;
        #pragma unroll
        for (int n = 0; n < NC; ++n) sum += __expf(scores_s[n] - m);
        const float p = __expf(scores_s[tid] - m) / sum;
        atomicAdd(out_row + ids[(size_t)b * NC + tid], p);
    }
}

extern "C" void kernel_launch(void* const* d_in, const int* in_sizes, int n_in,
                              void* d_out, int out_size, void* d_ws, size_t ws_size,
                              hipStream_t stream) {
    const float* x    = (const float*)d_in[0];
    const float* emb  = (const float*)d_in[1];
    const int*   ids  = (const int*)d_in[2];
    // d_in[3] = prob (zeros) — unused
    const float* W    = (const float*)d_in[4];
    const float* bias = (const float*)d_in[5];
    float*       out  = (float*)d_out;

    const int  B  = in_sizes[0] / EC;          // 4096
    const long n4 = (long)B * VOCAB / 4;       // 40,960,000 float4
    const size_t ws_needed = (size_t)B * NC * sizeof(float);   // 800 KB

    if (ws_size >= ws_needed) {
        float* pws = (float*)d_ws;
        hipLaunchKernelGGL(EmbDotSoftMax_hybrid_kernel,
                           dim3(FILL_BLOCKS + B), dim3(128), 0, stream,
                           x, emb, W, bias, out, pws, n4);
        hipLaunchKernelGGL(EmbDotSoftMax_merge_kernel,
                           dim3((B * NC + 255) / 256), dim3(256), 0, stream,
                           ids, pws, out, B * NC);
    } else {
        hipLaunchKernelGGL(EmbDotSoftMax_fill_fb,
                           dim3(2048), dim3(256), 0, stream,
                           reinterpret_cast<float4*>(out), n4);
        hipLaunchKernelGGL(EmbDotSoftMax_scatter_fb,
                           dim3(B), dim3(128), 0, stream,
                           x, emb, ids, W, bias, out);
    }
}